// Round 12
// baseline (123.863 us; speedup 1.0000x reference)
//
#include <hip/hip_runtime.h>

#define NV 1448
#define JD 4344    // 3*NV
#define CC 256
#define BB 64
#define QQ 128     // 2*BB
#define QCOLS 362  // NV/4, columns per chamfer block
#define NROW (2 * BB * NV)  // 185344 row-slots (dir x b x row)

// ---------------------------------------------------------------------------
// K1: global average pool over H*W=64 -> latT[c][q], q = t*64+b.
// Thread 0 zeroes the combine accumulator.
// ---------------------------------------------------------------------------
__global__ __launch_bounds__(256) void pool_kernel(const float* __restrict__ inp,
                                                   const float* __restrict__ tgt,
                                                   float* __restrict__ latT,
                                                   unsigned long long* __restrict__ acc) {
    int gid  = blockIdx.x * 256 + threadIdx.x;
    if (gid == 0) { acc[0] = 0ull; acc[1] = 0ull; }
    int lane = gid & 15;
    int row  = gid >> 4;                          // (t,b,c) flat, 32768 rows
    if (row >= 2 * BB * CC) return;
    int t  = row >> 14;                           // BB*CC = 16384
    int bc = row & 16383;
    const float* src = (t ? tgt : inp) + (size_t)bc * 64;
    float4 v = reinterpret_cast<const float4*>(src)[lane];
    float s = (v.x + v.y) + (v.z + v.w);
    s += __shfl_xor(s, 1);
    s += __shfl_xor(s, 2);
    s += __shfl_xor(s, 4);
    s += __shfl_xor(s, 8);
    if (lane == 0) {
        int b = bc >> 8, c = bc & 255;
        latT[c * QQ + t * BB + b] = s * (1.0f / 64.0f);
    }
}

// ---------------------------------------------------------------------------
// K2: decode GEMM v4 — K split across the block's 4 waves.
// grid (272 jt, 2 L, 2 qh) x 256 thr; block covers 16j x 64q, K=256.
// Wave w processes k-chunks {w*32, w*32+128} in a PRIVATE 10KB LDS quarter:
// no __syncthreads in the main loop (within-wave ds_write->ds_read only
// needs lgkmcnt, which the compiler inserts). 16 waves/CU = 4/SIMD hides
// LDS latency (prev versions ran at 1 wave/SIMD -> ~26us vs 14.5 floor).
// Per thread: 4j x 4q acc, 8 fma per ds_read_b128 (proven blocking).
// Epilogue: one barrier + LDS reduce of the 4 partial acc sets.
// ---------------------------------------------------------------------------
__global__ __launch_bounds__(256, 4) void decode_kernel(const float* __restrict__ latT,
                                                        const float* __restrict__ muL,
                                                        const float* __restrict__ deltaL,
                                                        const float* __restrict__ muR,
                                                        const float* __restrict__ deltaR,
                                                        const int* __restrict__ labels,
                                                        float* __restrict__ pts3) {
    const int jt = blockIdx.x;                 // 272 tiles of 16 j
    const int L  = blockIdx.y;
    const int qh = blockIdx.z;                 // q half: 64 q's
    const float* __restrict__ delta = L ? deltaR : deltaL;
    const float* __restrict__ mu    = L ? muR : muL;
    const int j0   = jt * 16;
    const int tid  = threadIdx.x;
    const int w    = tid >> 6;                 // wave 0..3
    const int lane = tid & 63;
    const int jl   = lane & 3;                 // 4 j-lanes x 4 j = 16 j
    const int qg   = lane >> 2;                // 16 q-lanes x 4 q = 64 q

    __shared__ float lds[10240];               // 40KB: 4 x (AsT 512 + Bs 2048)
    float* AsT = lds + w * 2560;               // [32][16]  (k-major)
    float* Bs  = AsT + 512;                    // [32][64]

    float acc[4][4];
#pragma unroll
    for (int u = 0; u < 4; ++u)
#pragma unroll
        for (int v = 0; v < 4; ++v) acc[u][v] = 0.f;

    const float4* latT4 = reinterpret_cast<const float4*>(latT);

#pragma unroll
    for (int c = 0; c < 2; ++c) {
        const int kc = w * 32 + c * 128;       // this wave's k-chunk
        // stage AsT: 16 j x 32 k = 128 float4, 2/lane (transposed scatter)
#pragma unroll
        for (int it = 0; it < 2; ++it) {
            int idx = it * 64 + lane;
            int kq  = idx & 7;                 // float4-chunk of k
            int r   = idx >> 3;                // j row 0..15
            int j   = j0 + r;
            float4 v = make_float4(0.f, 0.f, 0.f, 0.f);
            if (j < JD)
                v = *reinterpret_cast<const float4*>(delta + (size_t)j * CC + kc + kq * 4);
            AsT[(kq * 4 + 0) * 16 + r] = v.x;
            AsT[(kq * 4 + 1) * 16 + r] = v.y;
            AsT[(kq * 4 + 2) * 16 + r] = v.z;
            AsT[(kq * 4 + 3) * 16 + r] = v.w;
        }
        // stage Bs: 32 k x 64 q = 512 float4, 8/lane, coalesced
#pragma unroll
        for (int it = 0; it < 8; ++it) {
            int idx = it * 64 + lane;
            int qi  = idx & 15;
            int k   = idx >> 4;
            reinterpret_cast<float4*>(Bs)[k * 16 + qi] =
                latT4[(size_t)(kc + k) * 32 + qh * 16 + qi];
        }
        // compute (compiler inserts lgkmcnt between same-wave write/read)
#pragma unroll
        for (int k4 = 0; k4 < 32; k4 += 4) {
#pragma unroll
            for (int kk = 0; kk < 4; ++kk) {
                float4 a = *reinterpret_cast<const float4*>(&AsT[(k4 + kk) * 16 + jl * 4]);
                float4 b = *reinterpret_cast<const float4*>(&Bs[(k4 + kk) * 64 + qg * 4]);
                float av[4] = {a.x, a.y, a.z, a.w};
                float bv[4] = {b.x, b.y, b.z, b.w};
#pragma unroll
                for (int u = 0; u < 4; ++u)
#pragma unroll
                    for (int v = 0; v < 4; ++v)
                        acc[u][v] = fmaf(av[u], bv[v], acc[u][v]);
            }
        }
    }

    // cross-wave reduction: Red4[lane][w*4+u] (stride 17 float4 = no conflicts)
    __syncthreads();
    float4* red4 = reinterpret_cast<float4*>(lds);
#pragma unroll
    for (int u = 0; u < 4; ++u)
        red4[lane * 17 + w * 4 + u] = make_float4(acc[u][0], acc[u][1], acc[u][2], acc[u][3]);
    __syncthreads();

    if (w == 0) {
#pragma unroll
        for (int u = 0; u < 4; ++u) {
#pragma unroll
            for (int ww = 1; ww < 4; ++ww) {
                float4 p = red4[lane * 17 + ww * 4 + u];
                acc[u][0] += p.x; acc[u][1] += p.y; acc[u][2] += p.z; acc[u][3] += p.w;
            }
        }
        int j = j0 + jl * 4;
        if (j + 3 < JD) {                      // JD%4==0: full quad or skip
            float4 m = *reinterpret_cast<const float4*>(mu + j);
#pragma unroll
            for (int v = 0; v < 4; ++v) {
                int q = qh * 64 + qg * 4 + v;
                int b = q & 63;
                if (labels[b] == L) {
                    float4 o = make_float4(acc[0][v] + m.x, acc[1][v] + m.y,
                                           acc[2][v] + m.z, acc[3][v] + m.w);
                    *reinterpret_cast<float4*>(pts3 + (size_t)q * JD + j) = o;
                }
            }
        }
    }
}

// ---------------------------------------------------------------------------
// K3: chamfer partial row-mins, pack fused, forced v_min3_f32.
// grid (chunk 0..2, b 0..63, z 0..7: dir=z>>2, q=z&3); 1536 blocks = 6/CU.
// ~92% of the 3.5-instr/pair fp32 VALU roofline (R8 calibration).
// ---------------------------------------------------------------------------
__global__ __launch_bounds__(256) void chamfer_kernel(const float* __restrict__ pts3,
                                                      float* __restrict__ pmin) {
    const int chunk = blockIdx.x;
    const int b     = blockIdx.y;
    const int dir   = blockIdx.z >> 2;
    const int q     = blockIdx.z & 3;
    const int qa = dir * BB + b;
    const int qb = (1 - dir) * BB + b;
    const float* __restrict__ A3 = pts3 + (size_t)qa * JD;
    const float* __restrict__ B3 = pts3 + (size_t)qb * JD + q * (QCOLS * 3);

    __shared__ float4 Bs[QCOLS];
    const int tid = threadIdx.x;
    for (int i = tid; i < QCOLS; i += 256) {
        float x = B3[3 * i], y = B3[3 * i + 1], z = B3[3 * i + 2];
        Bs[i] = make_float4(-2.f * x, -2.f * y, -2.f * z, fmaf(x, x, fmaf(y, y, z * z)));
    }
    __syncthreads();

    int r0 = chunk * 512 + tid;
    int r1 = r0 + 256;
    float a0x = 0.f, a0y = 0.f, a0z = 0.f, a0w = 0.f;
    float a1x = 0.f, a1y = 0.f, a1z = 0.f, a1w = 0.f;
    if (r0 < NV) {
        a0x = A3[3 * r0]; a0y = A3[3 * r0 + 1]; a0z = A3[3 * r0 + 2];
        a0w = fmaf(a0x, a0x, fmaf(a0y, a0y, a0z * a0z));
    }
    if (r1 < NV) {
        a1x = A3[3 * r1]; a1y = A3[3 * r1 + 1]; a1z = A3[3 * r1 + 2];
        a1w = fmaf(a1x, a1x, fmaf(a1y, a1y, a1z * a1z));
    }
    float m0 = 1e30f, m1 = 1e30f;

#pragma unroll 2
    for (int m = 0; m < QCOLS; m += 2) {
        float4 b0 = Bs[m];
        float4 b1 = Bs[m + 1];
        float d00 = fmaf(b0.x, a0x, fmaf(b0.y, a0y, fmaf(b0.z, a0z, b0.w)));
        float d01 = fmaf(b1.x, a0x, fmaf(b1.y, a0y, fmaf(b1.z, a0z, b1.w)));
        asm("v_min3_f32 %0, %0, %1, %2" : "+v"(m0) : "v"(d00), "v"(d01));
        float d10 = fmaf(b0.x, a1x, fmaf(b0.y, a1y, fmaf(b0.z, a1z, b0.w)));
        float d11 = fmaf(b1.x, a1x, fmaf(b1.y, a1y, fmaf(b1.z, a1z, b1.w)));
        asm("v_min3_f32 %0, %0, %1, %2" : "+v"(m1) : "v"(d10), "v"(d11));
    }

    size_t base = (size_t)q * NROW + (size_t)qa * NV;
    if (r0 < NV) pmin[base + r0] = m0 + a0w;
    if (r1 < NV) pmin[base + r1] = m1 + a1w;
}

// ---------------------------------------------------------------------------
// K3b: combine 4 quarter-mins, sqrt, block sums -> fixed-point atomic;
// last block writes out. 256 blocks x 724 rows exact.
// ---------------------------------------------------------------------------
__global__ __launch_bounds__(256) void combine_kernel(const float* __restrict__ pmin,
                                                      unsigned long long* __restrict__ acc,
                                                      float* __restrict__ out) {
    const int base = blockIdx.x * 724;
    const int tid  = threadIdx.x;
    float s = 0.f;
#pragma unroll
    for (int it = 0; it < 3; ++it) {
        int idx = it * 256 + tid;
        if (idx < 724) {
            int g = base + idx;
            float v = fminf(fminf(pmin[g], pmin[g + NROW]),
                            fminf(pmin[g + 2 * NROW], pmin[g + 3 * NROW]));
            s += sqrtf(fmaxf(v, 1e-12f));
        }
    }
    s += __shfl_xor(s, 1);
    s += __shfl_xor(s, 2);
    s += __shfl_xor(s, 4);
    s += __shfl_xor(s, 8);
    s += __shfl_xor(s, 16);
    s += __shfl_xor(s, 32);
    __shared__ float wsum[4];
    if ((tid & 63) == 0) wsum[tid >> 6] = s;
    __syncthreads();
    if (tid == 0) {
        float bs = wsum[0] + wsum[1] + wsum[2] + wsum[3];
        unsigned long long qv = (unsigned long long)((double)bs * 16777216.0); // 2^24 fixed pt
        atomicAdd(acc, qv);
        __threadfence();
        unsigned long long done = atomicAdd(acc + 1, 1ull);
        if (done == 255) {
            __threadfence();
            unsigned long long total = atomicAdd(acc, 0ull);
            out[0] = (float)((double)total * (0x1p-24 / (64.0 * 1448.0)));
        }
    }
}

extern "C" void kernel_launch(void* const* d_in, const int* in_sizes, int n_in,
                              void* d_out, int out_size, void* d_ws, size_t ws_size,
                              hipStream_t stream) {
    const float* inp    = (const float*)d_in[0];
    const float* tgt    = (const float*)d_in[1];
    const int*   labels = (const int*)d_in[2];
    const float* muL    = (const float*)d_in[3];
    const float* deltaL = (const float*)d_in[4];
    const float* muR    = (const float*)d_in[5];
    const float* deltaR = (const float*)d_in[6];
    float* out = (float*)d_out;

    char* ws = (char*)d_ws;
    float* latT = (float*)ws;                                   // 128*256*4 = 131072 B
    float* pts3 = (float*)(ws + 131072);                        // 128*4344*4 = 2224128 B
    float* pmin = (float*)(ws + 131072 + 2224128);              // 4*185344*4 = 2965504 B
    unsigned long long* acc = (unsigned long long*)(ws + 131072 + 2224128 + 2965504);

    hipLaunchKernelGGL(pool_kernel, dim3(2048), dim3(256), 0, stream, inp, tgt, latT, acc);
    hipLaunchKernelGGL(decode_kernel, dim3(272, 2, 2), dim3(256), 0, stream,
                       latT, muL, deltaL, muR, deltaR, labels, pts3);
    hipLaunchKernelGGL(chamfer_kernel, dim3(3, 64, 8), dim3(256), 0, stream,
                       pts3, pmin);
    hipLaunchKernelGGL(combine_kernel, dim3(256), dim3(256), 0, stream, pmin, acc, out);
}

// Round 13
// 72.286 us; speedup vs baseline: 1.7135x; 1.7135x over previous
//
#include <hip/hip_runtime.h>

#define NV 1448
#define JD 4344    // 3*NV
#define CC 256
#define BB 64
#define QQ 128     // 2*BB
#define QCOLS 362  // NV/4, columns per chamfer block
#define NROW (2 * BB * NV)  // 185344 row-slots (dir x b x row)

// ---------------------------------------------------------------------------
// K1: global average pool over H*W=64 -> latQ[q][c], q = t*64+b.
// Thread 0 zeroes acc; block 0 / thread 0 builds the label-sorted q
// permutation (4 groups of 64: side0 in groups 0-1, side1 in groups 2-3,
// -1 padded) — depends only on labels, safe to run concurrently with pool.
// ---------------------------------------------------------------------------
__global__ __launch_bounds__(256) void pool_kernel(const float* __restrict__ inp,
                                                   const float* __restrict__ tgt,
                                                   float* __restrict__ latQ,
                                                   unsigned long long* __restrict__ acc,
                                                   const int* __restrict__ labels,
                                                   int* __restrict__ qperm,
                                                   int* __restrict__ gside) {
    int gid  = blockIdx.x * 256 + threadIdx.x;
    if (gid == 0) {
        acc[0] = 0ull; acc[1] = 0ull;
        int pos = 0;
        for (int q = 0; q < QQ; ++q) if (labels[q & 63] == 0) qperm[pos++] = q;
        gside[0] = (pos > 0)  ? 0 : -1;
        gside[1] = (pos > 64) ? 0 : -1;
        for (int i = pos; i < 128; ++i) qperm[i] = -1;
        int pos2 = 128;
        for (int q = 0; q < QQ; ++q) if (labels[q & 63] == 1) qperm[pos2++] = q;
        gside[2] = (pos2 > 128) ? 1 : -1;
        gside[3] = (pos2 > 192) ? 1 : -1;
        for (int i = pos2; i < 256; ++i) qperm[i] = -1;
    }
    int lane = gid & 15;
    int row  = gid >> 4;                          // (t,b,c) flat, 32768 rows
    if (row >= 2 * BB * CC) return;
    int t  = row >> 14;                           // BB*CC = 16384
    int bc = row & 16383;
    const float* src = (t ? tgt : inp) + (size_t)bc * 64;
    float4 v = reinterpret_cast<const float4*>(src)[lane];
    float s = (v.x + v.y) + (v.z + v.w);
    s += __shfl_xor(s, 1);
    s += __shfl_xor(s, 2);
    s += __shfl_xor(s, 4);
    s += __shfl_xor(s, 8);
    if (lane == 0) {
        int b = bc >> 8, c = bc & 255;
        latQ[(size_t)(t * 64 + b) * CC + c] = s * (1.0f / 64.0f);
    }
}

// ---------------------------------------------------------------------------
// K2: decode GEMM v5 — R11's 1-wave blocks + label-sorted q groups.
// grid (272 jt, 4 group) x 64 thr; group is side-uniform (presorted), so
// every FMA lands in a written output: executed work HALVED vs R10-R12
// (which computed both sides for every q). Empty groups exit immediately.
// Per block: 16 j x 64 q, 4j x 4q per thread, 8 fma per ds_read_b128.
// latQ is [q][c] so permuted B-staging stays f4-coalesced along k.
// ---------------------------------------------------------------------------
__global__ __launch_bounds__(64, 4) void decode_kernel(const float* __restrict__ latQ,
                                                       const float* __restrict__ muL,
                                                       const float* __restrict__ deltaL,
                                                       const float* __restrict__ muR,
                                                       const float* __restrict__ deltaR,
                                                       const int* __restrict__ qperm,
                                                       const int* __restrict__ gside,
                                                       float* __restrict__ pts3) {
    const int g    = blockIdx.y;               // q-group 0..3
    const int side = gside[g];
    if (side < 0) return;
    const int jt = blockIdx.x;                 // 272 tiles of 16 j
    const float* __restrict__ delta = side ? deltaR : deltaL;
    const float* __restrict__ mu    = side ? muR : muL;
    const int j0   = jt * 16;
    const int lane = threadIdx.x;              // 0..63
    const int jl   = lane & 3;                 // 4 j-lanes x 4 j
    const int qg   = lane >> 2;                // 16 q-lanes x 4 q

    __shared__ float AsT[32][16];              // [k][j]
    __shared__ float Bs[32][64];               // [k][qslot]
    __shared__ int   qs_sh[64];

    // my lane's staging q (one per lane) and my compute q's (4 per thread)
    int qmine = qperm[g * 64 + lane];
    qs_sh[lane] = qmine;
    const float* __restrict__ brow = latQ + (size_t)(qmine < 0 ? 0 : qmine) * CC;

    float acc[4][4];
#pragma unroll
    for (int u = 0; u < 4; ++u)
#pragma unroll
        for (int v = 0; v < 4; ++v) acc[u][v] = 0.f;

    for (int kc = 0; kc < CC; kc += 32) {
        __syncthreads();
        // stage AsT: 16 j x 32 k = 128 float4, 2/lane (transposed scatter)
#pragma unroll
        for (int it = 0; it < 2; ++it) {
            int idx = it * 64 + lane;
            int kq  = idx & 7;                 // float4-chunk of k
            int r   = idx >> 3;                // j row 0..15
            int j   = j0 + r;
            float4 v = make_float4(0.f, 0.f, 0.f, 0.f);
            if (j < JD)
                v = *reinterpret_cast<const float4*>(delta + (size_t)j * CC + kc + kq * 4);
            AsT[kq * 4 + 0][r] = v.x;
            AsT[kq * 4 + 1][r] = v.y;
            AsT[kq * 4 + 2][r] = v.z;
            AsT[kq * 4 + 3][r] = v.w;
        }
        // stage Bs: lane owns q-slot `lane`; 8 f4 reads along k, scatter to
        // Bs[k][lane] (consecutive lanes -> consecutive banks, conflict-free)
#pragma unroll
        for (int i = 0; i < 8; ++i) {
            float4 v = *reinterpret_cast<const float4*>(brow + kc + i * 4);
            Bs[i * 4 + 0][lane] = v.x;
            Bs[i * 4 + 1][lane] = v.y;
            Bs[i * 4 + 2][lane] = v.z;
            Bs[i * 4 + 3][lane] = v.w;
        }
        __syncthreads();

#pragma unroll
        for (int k4 = 0; k4 < 32; k4 += 4) {
#pragma unroll
            for (int kk = 0; kk < 4; ++kk) {
                float4 a = *reinterpret_cast<const float4*>(&AsT[k4 + kk][jl * 4]);
                float4 b = *reinterpret_cast<const float4*>(&Bs[k4 + kk][qg * 4]);
                float av[4] = {a.x, a.y, a.z, a.w};
                float bv[4] = {b.x, b.y, b.z, b.w};
#pragma unroll
                for (int u = 0; u < 4; ++u)
#pragma unroll
                    for (int v = 0; v < 4; ++v)
                        acc[u][v] = fmaf(av[u], bv[v], acc[u][v]);
            }
        }
    }

    int j = j0 + jl * 4;
    if (j + 3 < JD) {                          // JD%4==0: full quad or skip
        float4 m = *reinterpret_cast<const float4*>(mu + j);
#pragma unroll
        for (int v = 0; v < 4; ++v) {
            int q = qs_sh[qg * 4 + v];
            if (q >= 0) {
                float4 o = make_float4(acc[0][v] + m.x, acc[1][v] + m.y,
                                       acc[2][v] + m.z, acc[3][v] + m.w);
                *reinterpret_cast<float4*>(pts3 + (size_t)q * JD + j) = o;
            }
        }
    }
}

// ---------------------------------------------------------------------------
// K3: chamfer partial row-mins, pack fused, forced v_min3_f32 (R11, proven).
// grid (chunk 0..2, b 0..63, z 0..7: dir=z>>2, q=z&3); 1536 blocks = 6/CU.
// ---------------------------------------------------------------------------
__global__ __launch_bounds__(256) void chamfer_kernel(const float* __restrict__ pts3,
                                                      float* __restrict__ pmin) {
    const int chunk = blockIdx.x;
    const int b     = blockIdx.y;
    const int dir   = blockIdx.z >> 2;
    const int q     = blockIdx.z & 3;
    const int qa = dir * BB + b;
    const int qb = (1 - dir) * BB + b;
    const float* __restrict__ A3 = pts3 + (size_t)qa * JD;
    const float* __restrict__ B3 = pts3 + (size_t)qb * JD + q * (QCOLS * 3);

    __shared__ float4 Bs[QCOLS];
    const int tid = threadIdx.x;
    for (int i = tid; i < QCOLS; i += 256) {
        float x = B3[3 * i], y = B3[3 * i + 1], z = B3[3 * i + 2];
        Bs[i] = make_float4(-2.f * x, -2.f * y, -2.f * z, fmaf(x, x, fmaf(y, y, z * z)));
    }
    __syncthreads();

    int r0 = chunk * 512 + tid;
    int r1 = r0 + 256;
    float a0x = 0.f, a0y = 0.f, a0z = 0.f, a0w = 0.f;
    float a1x = 0.f, a1y = 0.f, a1z = 0.f, a1w = 0.f;
    if (r0 < NV) {
        a0x = A3[3 * r0]; a0y = A3[3 * r0 + 1]; a0z = A3[3 * r0 + 2];
        a0w = fmaf(a0x, a0x, fmaf(a0y, a0y, a0z * a0z));
    }
    if (r1 < NV) {
        a1x = A3[3 * r1]; a1y = A3[3 * r1 + 1]; a1z = A3[3 * r1 + 2];
        a1w = fmaf(a1x, a1x, fmaf(a1y, a1y, a1z * a1z));
    }
    float m0 = 1e30f, m1 = 1e30f;

#pragma unroll 2
    for (int m = 0; m < QCOLS; m += 2) {
        float4 b0 = Bs[m];
        float4 b1 = Bs[m + 1];
        float d00 = fmaf(b0.x, a0x, fmaf(b0.y, a0y, fmaf(b0.z, a0z, b0.w)));
        float d01 = fmaf(b1.x, a0x, fmaf(b1.y, a0y, fmaf(b1.z, a0z, b1.w)));
        asm("v_min3_f32 %0, %0, %1, %2" : "+v"(m0) : "v"(d00), "v"(d01));
        float d10 = fmaf(b0.x, a1x, fmaf(b0.y, a1y, fmaf(b0.z, a1z, b0.w)));
        float d11 = fmaf(b1.x, a1x, fmaf(b1.y, a1y, fmaf(b1.z, a1z, b1.w)));
        asm("v_min3_f32 %0, %0, %1, %2" : "+v"(m1) : "v"(d10), "v"(d11));
    }

    size_t base = (size_t)q * NROW + (size_t)qa * NV;
    if (r0 < NV) pmin[base + r0] = m0 + a0w;
    if (r1 < NV) pmin[base + r1] = m1 + a1w;
}

// ---------------------------------------------------------------------------
// K3b: combine 4 quarter-mins, sqrt, block sums -> fixed-point atomic;
// last block writes out. 256 blocks x 724 rows exact.
// ---------------------------------------------------------------------------
__global__ __launch_bounds__(256) void combine_kernel(const float* __restrict__ pmin,
                                                      unsigned long long* __restrict__ acc,
                                                      float* __restrict__ out) {
    const int base = blockIdx.x * 724;
    const int tid  = threadIdx.x;
    float s = 0.f;
#pragma unroll
    for (int it = 0; it < 3; ++it) {
        int idx = it * 256 + tid;
        if (idx < 724) {
            int g = base + idx;
            float v = fminf(fminf(pmin[g], pmin[g + NROW]),
                            fminf(pmin[g + 2 * NROW], pmin[g + 3 * NROW]));
            s += sqrtf(fmaxf(v, 1e-12f));
        }
    }
    s += __shfl_xor(s, 1);
    s += __shfl_xor(s, 2);
    s += __shfl_xor(s, 4);
    s += __shfl_xor(s, 8);
    s += __shfl_xor(s, 16);
    s += __shfl_xor(s, 32);
    __shared__ float wsum[4];
    if ((tid & 63) == 0) wsum[tid >> 6] = s;
    __syncthreads();
    if (tid == 0) {
        float bs = wsum[0] + wsum[1] + wsum[2] + wsum[3];
        unsigned long long qv = (unsigned long long)((double)bs * 16777216.0); // 2^24 fixed pt
        atomicAdd(acc, qv);
        __threadfence();
        unsigned long long done = atomicAdd(acc + 1, 1ull);
        if (done == 255) {
            __threadfence();
            unsigned long long total = atomicAdd(acc, 0ull);
            out[0] = (float)((double)total * (0x1p-24 / (64.0 * 1448.0)));
        }
    }
}

extern "C" void kernel_launch(void* const* d_in, const int* in_sizes, int n_in,
                              void* d_out, int out_size, void* d_ws, size_t ws_size,
                              hipStream_t stream) {
    const float* inp    = (const float*)d_in[0];
    const float* tgt    = (const float*)d_in[1];
    const int*   labels = (const int*)d_in[2];
    const float* muL    = (const float*)d_in[3];
    const float* deltaL = (const float*)d_in[4];
    const float* muR    = (const float*)d_in[5];
    const float* deltaR = (const float*)d_in[6];
    float* out = (float*)d_out;

    char* ws = (char*)d_ws;
    float* latQ = (float*)ws;                                   // 128*256*4 = 131072 B
    float* pts3 = (float*)(ws + 131072);                        // 128*4344*4 = 2224128 B
    float* pmin = (float*)(ws + 131072 + 2224128);              // 4*185344*4 = 2965504 B
    unsigned long long* acc = (unsigned long long*)(ws + 131072 + 2224128 + 2965504);
    int* qperm = (int*)((char*)acc + 256);                      // 256*4
    int* gside = qperm + 256;                                   // 4*4

    hipLaunchKernelGGL(pool_kernel, dim3(2048), dim3(256), 0, stream,
                       inp, tgt, latQ, acc, labels, qperm, gside);
    hipLaunchKernelGGL(decode_kernel, dim3(272, 4), dim3(64), 0, stream,
                       latQ, muL, deltaL, muR, deltaR, qperm, gside, pts3);
    hipLaunchKernelGGL(chamfer_kernel, dim3(3, 64, 8), dim3(256), 0, stream,
                       pts3, pmin);
    hipLaunchKernelGGL(combine_kernel, dim3(256), dim3(256), 0, stream, pmin, acc, out);
}